// Round 7
// baseline (368.116 us; speedup 1.0000x reference)
//
#include <hip/hip_runtime.h>

// GraphSAGE 3-layer encoder. R16: chunk-sorted ELL gather.
// R6 evidence: ILP x2 and occupancy x2 both null -> gather is bound by the
// memory system (650k lines/layer past L2 at ~900cy). Fix locality instead:
// counting-sort each node's neighbor list by src-chunk (16 chunks x 1.6MB of
// h). Co-resident blocks walk lists in chunk order => instantaneous read
// window ~ILP*0.8MB fits per-XCD L2 => misses become hits. Gather ILP-4
// (window ~4MB; ILP proven a null knob otherwise). Build becomes 3-pass:
// count (merged with casts) -> per-node prefix -> place.
#define N_NODES 50000
#define NP 50048          // padded to 1564*32 rows
#define N_EDGES 800000
#define N_GRAPHS 512
#define F 128
#define ELLW 64           // Poisson(16): P(deg>=64) ~ e^-125
#define ZROW N_NODES      // guaranteed all-zero row in X/HA/HB

#define FILL_BLOCKS 3125    // N_EDGES/256, 1 edge/thread
#define CASTX_BLOCKS 3128   // NP*F/8/256
#define CASTW_BLOCKS 48     // 6*16384/8/256

typedef __bf16 bf16x8 __attribute__((ext_vector_type(8)));
typedef float f32x4 __attribute__((ext_vector_type(4)));
typedef float f32x4v __attribute__((ext_vector_type(4)));   // nt-load friendly
typedef unsigned short ushort_t;
typedef unsigned int uint_t;

__device__ inline ushort_t f2bf(float f) {  // RTNE
    uint_t u = __float_as_uint(f);
    u += 0x7FFFu + ((u >> 16) & 1u);
    return (ushort_t)(u >> 16);
}
__device__ inline float bf2f(ushort_t u) {
    return __uint_as_float(((uint_t)u) << 16);
}
__device__ inline uint_t pack2(float a, float b) {
    return (uint_t)f2bf(a) | ((uint_t)f2bf(b) << 16);
}
__device__ inline void addrow(float* a, uint4 v) {
    a[0] += __uint_as_float(v.x << 16); a[1] += __uint_as_float(v.x & 0xFFFF0000u);
    a[2] += __uint_as_float(v.y << 16); a[3] += __uint_as_float(v.y & 0xFFFF0000u);
    a[4] += __uint_as_float(v.z << 16); a[5] += __uint_as_float(v.z & 0xFFFF0000u);
    a[6] += __uint_as_float(v.w << 16); a[7] += __uint_as_float(v.w & 0xFFFF0000u);
}

// ---- pass 1 merged: per-(node,chunk) count + bf16 casts ----
__global__ __launch_bounds__(256) void k_build(
    const float* __restrict__ x,
    const float* __restrict__ w0, const float* __restrict__ w1,
    const float* __restrict__ w2, const float* __restrict__ w3,
    const float* __restrict__ w4, const float* __restrict__ w5,
    const int* __restrict__ src, const int* __restrict__ dst,
    ushort_t* __restrict__ X, ushort_t* __restrict__ WB,
    int* __restrict__ cnt8, int chdiv, int ch) {
    int b = blockIdx.x;
    int t = threadIdx.x;
    if (b < FILL_BLOCKS) {
        int e = b * 256 + t;
        int d = dst[e];
        int c = src[e] / chdiv;
        atomicAdd(&cnt8[d * ch + c], 1);
    } else if (b < FILL_BLOCKS + CASTX_BLOCKS) {
        int i = ((b - FILL_BLOCKS) * 256 + t) * 8;
        uint4 o = make_uint4(0, 0, 0, 0);
        if (i < N_NODES * F) {  // boundary 8-aligned: no straddle
            f32x4v v0 = __builtin_nontemporal_load((const f32x4v*)&x[i]);
            f32x4v v1 = __builtin_nontemporal_load((const f32x4v*)&x[i + 4]);
            o = make_uint4(pack2(v0.x, v0.y), pack2(v0.z, v0.w),
                           pack2(v1.x, v1.y), pack2(v1.z, v1.w));
        }
        *(uint4*)&X[i] = o;  // pads (>=N_NODES) written as zeros: ZROW source
    } else {
        int idx = (b - FILL_BLOCKS - CASTX_BLOCKS) * 256 + t;  // 8-elem groups
        int m = idx >> 11;
        int o = (idx & 2047) * 8;
        const float* s = w0;
        if (m == 1) s = w1; else if (m == 2) s = w2; else if (m == 3) s = w3;
        else if (m == 4) s = w4; else if (m == 5) s = w5;
        float4 v0 = *(const float4*)&s[o];
        float4 v1 = *(const float4*)&s[o + 4];
        *(uint4*)&WB[m * 16384 + o] =
            make_uint4(pack2(v0.x, v0.y), pack2(v0.z, v0.w),
                       pack2(v1.x, v1.y), pack2(v1.z, v1.w));
    }
}

// ---- pass 2: in-place exclusive prefix over each node's ch counters ----
__global__ __launch_bounds__(256) void k_prefix(int* __restrict__ cnt8, int ch) {
    int n = blockIdx.x * 256 + threadIdx.x;
    if (n >= NP) return;
    if (ch == 16) {
        int4* p = (int4*)(cnt8 + (size_t)n * 16);
        int4 a = p[0], b = p[1], c = p[2], d = p[3];
        int v[16] = {a.x, a.y, a.z, a.w, b.x, b.y, b.z, b.w,
                     c.x, c.y, c.z, c.w, d.x, d.y, d.z, d.w};
        int run = 0;
#pragma unroll
        for (int j = 0; j < 16; j++) { int u = v[j]; v[j] = run; run += u; }
        p[0] = make_int4(v[0], v[1], v[2], v[3]);
        p[1] = make_int4(v[4], v[5], v[6], v[7]);
        p[2] = make_int4(v[8], v[9], v[10], v[11]);
        p[3] = make_int4(v[12], v[13], v[14], v[15]);
    } else {
        int base = n * ch;
        int run = 0;
        for (int j = 0; j < ch; j++) {
            int u = cnt8[base + j]; cnt8[base + j] = run; run += u;
        }
    }
}

// ---- pass 3: place edges at sorted positions ----
__global__ __launch_bounds__(256) void k_place(
    const int* __restrict__ src, const int* __restrict__ dst,
    int* __restrict__ cnt8, ushort_t* __restrict__ ell, int chdiv, int ch) {
    int e = blockIdx.x * 256 + threadIdx.x;
    int d = dst[e];
    int s = src[e];
    int c = s / chdiv;
    int pos = atomicAdd(&cnt8[d * ch + c], 1);
    if (pos < ELLW) ell[((size_t)d << 6) + pos] = (ushort_t)s;
}
// after k_place: cnt8[n*ch + ch-1] == total degree of n.

// ---- fused layer, BM=32: gather-mean (ILP-4, chunk-sorted) + dual GEMM ----
// 1564 blocks x 256 thr. LDS: Ah 8KB + Agg 8KB, [kchunk][row]x16B layout.
__global__ __launch_bounds__(256) void k_layer(const ushort_t* __restrict__ h,
                                               const ushort_t* __restrict__ ell,
                                               const int* __restrict__ cnt8,
                                               const ushort_t* __restrict__ Wl,
                                               const ushort_t* __restrict__ Wr,
                                               const float* __restrict__ bias,
                                               ushort_t* __restrict__ out, int ch) {
    __shared__ uint4 AhS[512];     // 8 KB: h rows, chunk-major [16][32] x16B
    __shared__ uint4 AggS[512];    // 8 KB: agg rows, swizzled row^(chunk&7)
    ushort_t* Ah = (ushort_t*)AhS;
    ushort_t* Agg = (ushort_t*)AggS;

    int t = threadIdx.x;
    int w = t >> 6;
    int lane = t & 63;
    int bm = blockIdx.x * 32;
    int lane16 = t & 15;

    // -- stage own h rows (async GLL, drains at the barrier) --
#pragma unroll
    for (int p = 0; p < 2; p++) {
        int chunkA = p * 8 + w * 2;
        const ushort_t* gA =
            h + (size_t)(bm + (lane & 31)) * F + (chunkA + (lane >> 5)) * 8;
        ushort_t* lA = Ah + (size_t)(chunkA * 32) * 8;
        __builtin_amdgcn_global_load_lds(
            (const __attribute__((address_space(1))) void*)gA,
            (__attribute__((address_space(3))) void*)lA, 16, 0, 0);
    }

    // -- gather-mean 32 rows: 16 lanes/node, 16 nodes/round, 2 rounds, ILP-4.
    // List is chunk-sorted: co-resident waves at entry i read ~the same 2
    // chunks of h (~3-4MB window) => L2-resident. Evens->ax, odds->ay.
    const uint4* h4 = (const uint4*)h;
    int degs[2];
#pragma unroll
    for (int rnd = 0; rnd < 2; rnd++)
        degs[rnd] = min(cnt8[(size_t)(bm + rnd * 16 + (t >> 4)) * ch + ch - 1],
                        ELLW);

#pragma unroll
    for (int rnd = 0; rnd < 2; rnd++) {
        int r = rnd * 16 + (t >> 4);      // local row 0..31
        int n = bm + r;                   // global node (may be pad, deg=0)
        int deg = degs[rnd];
        const ushort_t* el = ell + ((size_t)n << 6);
        float ax[8], ay[8];
#pragma unroll
        for (int j = 0; j < 8; j++) { ax[j] = 0.f; ay[j] = 0.f; }
        for (int i = 0; i < deg; i += 4) {
            uint2 iv = *(const uint2*)(el + i);   // 4 sorted indices
            int s0 = iv.x & 0xFFFF, s1 = iv.x >> 16;
            int s2 = iv.y & 0xFFFF, s3 = iv.y >> 16;
            s1 = (i + 1 < deg) ? s1 : ZROW;
            s2 = (i + 2 < deg) ? s2 : ZROW;
            s3 = (i + 3 < deg) ? s3 : ZROW;
            uint4 v0 = h4[(size_t)s0 * 16 + lane16];
            uint4 v1 = h4[(size_t)s1 * 16 + lane16];
            uint4 v2 = h4[(size_t)s2 * 16 + lane16];
            uint4 v3 = h4[(size_t)s3 * 16 + lane16];
            addrow(ax, v0); addrow(ay, v1); addrow(ax, v2); addrow(ay, v3);
        }
        float sc = 1.0f / fmaxf((float)deg, 1.0f);
        uint4 o = make_uint4(
            pack2((ax[0] + ay[0]) * sc, (ax[1] + ay[1]) * sc),
            pack2((ax[2] + ay[2]) * sc, (ax[3] + ay[3]) * sc),
            pack2((ax[4] + ay[4]) * sc, (ax[5] + ay[5]) * sc),
            pack2((ax[6] + ay[6]) * sc, (ax[7] + ay[7]) * sc));
        AggS[lane16 * 32 + (r ^ (lane16 & 7))] = o;   // swizzled: chunk=lane16
    }
    __syncthreads();   // drains GLL (vmcnt) + ds_writes (lgkm)

    // -- dual GEMM: acc = Agg@Wl^T + Ah@Wr^T; B frags straight from L2.
    // Wave tile 16x64: wm=(w&1)*16, wn=(w>>1)*64; 1x4 frags x 4 ksteps.
    int wm = (w & 1) * 16;
    int wn = (w >> 1) * 64;
    int lrow = lane & 15;
    int kg = lane >> 4;

    f32x4 acc[4];
#pragma unroll
    for (int j = 0; j < 4; j++) acc[j] = (f32x4){0.f, 0.f, 0.f, 0.f};

#pragma unroll
    for (int ks = 0; ks < 4; ks++) {
        int kc = ks * 4 + kg;            // k-chunk 0..15
        int row = wm + lrow;
        bf16x8 aA = *(const bf16x8*)(Agg +
            (size_t)(kc * 32 + (row ^ (kc & 7))) * 8);   // match swizzle
        bf16x8 aH = *(const bf16x8*)(Ah + (size_t)(kc * 32 + row) * 8);
        bf16x8 bL[4], bR[4];
#pragma unroll
        for (int j = 0; j < 4; j++) {
            bL[j] = *(const bf16x8*)(Wl + (size_t)(wn + j * 16 + lrow) * F + kc * 8);
            bR[j] = *(const bf16x8*)(Wr + (size_t)(wn + j * 16 + lrow) * F + kc * 8);
        }
#pragma unroll
        for (int j = 0; j < 4; j++) {
            acc[j] = __builtin_amdgcn_mfma_f32_16x16x32_bf16(aA, bL[j], acc[j], 0, 0, 0);
            acc[j] = __builtin_amdgcn_mfma_f32_16x16x32_bf16(aH, bR[j], acc[j], 0, 0, 0);
        }
    }

    // epilogue: C/D map col=lane&15, row=(lane>>4)*4+reg.
    // Pad rows (>=N_NODES) written as EXPLICIT ZEROS (next layer's ZROW).
    int quad = lane >> 4;
#pragma unroll
    for (int j = 0; j < 4; j++) {
        int c = wn + j * 16 + lrow;
        float bj = bias[c];
#pragma unroll
        for (int r = 0; r < 4; r++) {
            int row = bm + wm + quad * 4 + r;
            float v = (row < N_NODES) ? fmaxf(acc[j][r] + bj, 0.0f) : 0.0f;
            out[(size_t)row * F + c] = f2bf(v);
        }
    }
}

// ---- mean pool: block per graph, 256 thr (2 halves/col), bsearch ----
__global__ __launch_bounds__(256) void k_pool(const ushort_t* __restrict__ h,
                                              const int* __restrict__ batch,
                                              float* __restrict__ out) {
    __shared__ float red[128];
    int g = blockIdx.x;
    int t = threadIdx.x;
    int col = t & 127;
    int half = t >> 7;
    int lo = 0, hi = N_NODES;
    while (lo < hi) {
        int m = (lo + hi) >> 1;
        if (batch[m] < g) lo = m + 1; else hi = m;
    }
    int start = lo;
    lo = start; hi = N_NODES;
    while (lo < hi) {
        int m = (lo + hi) >> 1;
        if (batch[m] < g + 1) lo = m + 1; else hi = m;
    }
    int end = lo;
    float s = 0.0f;
    for (int n = start + half; n < end; n += 2)
        s += bf2f(h[(size_t)n * F + col]);
    if (half) red[col] = s;
    __syncthreads();
    if (!half)
        out[g * F + col] = (s + red[col]) / fmaxf((float)(end - start), 1.0f);
}

extern "C" void kernel_launch(void* const* d_in, const int* in_sizes, int n_in,
                              void* d_out, int out_size, void* d_ws, size_t ws_size,
                              hipStream_t stream) {
    const float* x   = (const float*)d_in[0];
    const int*   ei  = (const int*)d_in[1];
    const int* batch = (const int*)d_in[2];
    const float* W1l = (const float*)d_in[3];
    const float* W1r = (const float*)d_in[4];
    const float* b1  = (const float*)d_in[5];
    const float* W2l = (const float*)d_in[6];
    const float* W2r = (const float*)d_in[7];
    const float* b2  = (const float*)d_in[8];
    const float* W3l = (const float*)d_in[9];
    const float* W3r = (const float*)d_in[10];
    const float* b3  = (const float*)d_in[11];
    float* out = (float*)d_out;

    const int* src = ei;
    const int* dst = ei + N_EDGES;

    // ws layout: X/HA/HB (3 x 12.81 MB) + WB (0.19) + ell (6.4) + cnt8
    ushort_t* X   = (ushort_t*)d_ws;          // NP*128 bf16
    ushort_t* HA  = X + (size_t)NP * F;
    ushort_t* HB  = HA + (size_t)NP * F;
    ushort_t* WB  = HB + (size_t)NP * F;      // 6*16384 bf16
    ushort_t* ell = WB + 6 * 16384;           // 50000*64 ushort
    int* cnt8 = (int*)(ell + (size_t)50000 * 64);

    // 16 chunks (3.2 MB cnt8) if the workspace has room (same footprint as
    // the previously-passing cs=16 layout); else ch=1 == unsorted fallback.
    size_t cnt8_off = (char*)cnt8 - (char*)d_ws;
    int ch = (ws_size >= cnt8_off + (size_t)NP * 16 * 4) ? 16 : 1;
    int chdiv = (ch == 16) ? 3125 : 50000;

    const ushort_t* Wb1l = WB;
    const ushort_t* Wb1r = WB + 16384;
    const ushort_t* Wb2l = WB + 2 * 16384;
    const ushort_t* Wb2r = WB + 3 * 16384;
    const ushort_t* Wb3l = WB + 4 * 16384;
    const ushort_t* Wb3r = WB + 5 * 16384;

    (void)hipMemsetAsync(cnt8, 0, (size_t)NP * ch * 4, stream);
    k_build<<<FILL_BLOCKS + CASTX_BLOCKS + CASTW_BLOCKS, 256, 0, stream>>>(
        x, W1l, W1r, W2l, W2r, W3l, W3r, src, dst, X, WB, cnt8, chdiv, ch);
    k_prefix<<<(NP + 255) / 256, 256, 0, stream>>>(cnt8, ch);
    k_place<<<FILL_BLOCKS, 256, 0, stream>>>(src, dst, cnt8, ell, chdiv, ch);

    const int layerBlocks = NP / 32;  // 1564 — ~6 blocks/CU, 24 waves/CU

    k_layer<<<layerBlocks, 256, 0, stream>>>(X, ell, cnt8, Wb1l, Wb1r, b1, HA, ch);
    k_layer<<<layerBlocks, 256, 0, stream>>>(HA, ell, cnt8, Wb2l, Wb2r, b2, HB, ch);
    k_layer<<<layerBlocks, 256, 0, stream>>>(HB, ell, cnt8, Wb3l, Wb3r, b3, HA, ch);

    k_pool<<<N_GRAPHS, 256, 0, stream>>>(HA, batch, out);
}

// Round 8
// 283.352 us; speedup vs baseline: 1.2991x; 1.2991x over previous
//
#include <hip/hip_runtime.h>

// GraphSAGE 3-layer encoder. R17: revert to R12/R3 config (best harness-timed:
// 293us) — unfused gather+linear, BM=64 MFMA linear, gather ILP-8, cs=16 —
// plus a vectorized k_pool (uint loads, 4 row-phases, ~2x fewer loads).
// R16's chunk-sort falsified: random graph => per-XCD first-touch floor
// (~102MB) >= measured 83.5MB FETCH; sorting can't reduce misses. Gather is
// at the memory-system random-line floor (ILP x2, occupancy x2 both null).
#define N_NODES 50000
#define NP 50048          // padded to 782*64 rows
#define N_EDGES 800000
#define N_GRAPHS 512
#define F 128
#define ELLW 64           // Poisson(16): P(deg>=64) ~ e^-125
#define ZROW N_NODES      // guaranteed all-zero row in X/HA/HB

#define FILL_BLOCKS 3125    // N_EDGES/256, 1 edge/thread
#define CASTX_BLOCKS 3128   // NP*F/8/256
#define CASTW_BLOCKS 48     // 6*16384/8/256

typedef __bf16 bf16x8 __attribute__((ext_vector_type(8)));
typedef float f32x4 __attribute__((ext_vector_type(4)));
typedef float f32x4v __attribute__((ext_vector_type(4)));   // nt-load friendly
typedef unsigned int u32x4v __attribute__((ext_vector_type(4)));
typedef unsigned short ushort_t;
typedef unsigned int uint_t;

__device__ inline ushort_t f2bf(float f) {  // RTNE
    uint_t u = __float_as_uint(f);
    u += 0x7FFFu + ((u >> 16) & 1u);
    return (ushort_t)(u >> 16);
}
__device__ inline float bf2f(ushort_t u) {
    return __uint_as_float(((uint_t)u) << 16);
}
__device__ inline uint_t pack2(float a, float b) {
    return (uint_t)f2bf(a) | ((uint_t)f2bf(b) << 16);
}
__device__ inline void addrow(float* a, uint4 v) {
    a[0] += __uint_as_float(v.x << 16); a[1] += __uint_as_float(v.x & 0xFFFF0000u);
    a[2] += __uint_as_float(v.y << 16); a[3] += __uint_as_float(v.y & 0xFFFF0000u);
    a[4] += __uint_as_float(v.z << 16); a[5] += __uint_as_float(v.z & 0xFFFF0000u);
    a[6] += __uint_as_float(v.w << 16); a[7] += __uint_as_float(v.w & 0xFFFF0000u);
}

// ---- merged build: ELL fill (1 edge/thread, line-padded cnt) + casts ----
__global__ __launch_bounds__(256) void k_build(
    const float* __restrict__ x,
    const float* __restrict__ w0, const float* __restrict__ w1,
    const float* __restrict__ w2, const float* __restrict__ w3,
    const float* __restrict__ w4, const float* __restrict__ w5,
    const int* __restrict__ src, const int* __restrict__ dst,
    ushort_t* __restrict__ X, ushort_t* __restrict__ WB,
    int* __restrict__ cnt, ushort_t* __restrict__ ell, int cs) {
    int b = blockIdx.x;
    int t = threadIdx.x;
    if (b < FILL_BLOCKS) {
        int e = b * 256 + t;
        int d = dst[e];
        int pos = atomicAdd(&cnt[(size_t)d * cs], 1);
        if (pos < ELLW) ell[((size_t)d << 6) + pos] = (ushort_t)src[e];
    } else if (b < FILL_BLOCKS + CASTX_BLOCKS) {
        int i = ((b - FILL_BLOCKS) * 256 + t) * 8;
        uint4 o = make_uint4(0, 0, 0, 0);
        if (i < N_NODES * F) {  // boundary 8-aligned: no straddle
            f32x4v v0 = __builtin_nontemporal_load((const f32x4v*)&x[i]);
            f32x4v v1 = __builtin_nontemporal_load((const f32x4v*)&x[i + 4]);
            o = make_uint4(pack2(v0.x, v0.y), pack2(v0.z, v0.w),
                           pack2(v1.x, v1.y), pack2(v1.z, v1.w));
        }
        *(uint4*)&X[i] = o;  // pads (>=N_NODES) written as zeros: ZROW source
    } else {
        int idx = (b - FILL_BLOCKS - CASTX_BLOCKS) * 256 + t;  // 8-elem groups
        int m = idx >> 11;
        int o = (idx & 2047) * 8;
        const float* s = w0;
        if (m == 1) s = w1; else if (m == 2) s = w2; else if (m == 3) s = w3;
        else if (m == 4) s = w4; else if (m == 5) s = w5;
        float4 v0 = *(const float4*)&s[o];
        float4 v1 = *(const float4*)&s[o + 4];
        *(uint4*)&WB[m * 16384 + o] =
            make_uint4(pack2(v0.x, v0.y), pack2(v0.z, v0.w),
                       pack2(v1.x, v1.y), pack2(v1.z, v1.w));
    }
}

// ---- gather-mean: 16 lanes/node, ILP-8, uint4 index loads, zero-row tail ----
__global__ __launch_bounds__(256) void k_gather(const ushort_t* __restrict__ h,
                                                const ushort_t* __restrict__ ell,
                                                const int* __restrict__ cnt,
                                                ushort_t* __restrict__ agg, int cs) {
    int t = blockIdx.x * 256 + threadIdx.x;
    int n = t >> 4;
    int lane16 = t & 15;
    if (n >= N_NODES) return;
    int deg = min(cnt[(size_t)n * cs], ELLW);
    const uint4* el4 = (const uint4*)(ell + ((size_t)n << 6));
    const uint4* h4 = (const uint4*)h;
    float ax[8], ay[8];
#pragma unroll
    for (int j = 0; j < 8; j++) { ax[j] = 0.f; ay[j] = 0.f; }
    for (int i = 0; i < deg; i += 8) {
        uint4 iv = el4[i >> 3];
        int s0 = iv.x & 0xFFFF, s1 = iv.x >> 16;
        int s2 = iv.y & 0xFFFF, s3 = iv.y >> 16;
        int s4 = iv.z & 0xFFFF, s5 = iv.z >> 16;
        int s6 = iv.w & 0xFFFF, s7 = iv.w >> 16;
        // entries beyond deg are uninitialized: clamp to a guaranteed-zero row
        s1 = (i + 1 < deg) ? s1 : ZROW;
        s2 = (i + 2 < deg) ? s2 : ZROW;
        s3 = (i + 3 < deg) ? s3 : ZROW;
        s4 = (i + 4 < deg) ? s4 : ZROW;
        s5 = (i + 5 < deg) ? s5 : ZROW;
        s6 = (i + 6 < deg) ? s6 : ZROW;
        s7 = (i + 7 < deg) ? s7 : ZROW;
        uint4 v0 = h4[(size_t)s0 * 16 + lane16];
        uint4 v1 = h4[(size_t)s1 * 16 + lane16];
        uint4 v2 = h4[(size_t)s2 * 16 + lane16];
        uint4 v3 = h4[(size_t)s3 * 16 + lane16];
        uint4 v4 = h4[(size_t)s4 * 16 + lane16];
        uint4 v5 = h4[(size_t)s5 * 16 + lane16];
        uint4 v6 = h4[(size_t)s6 * 16 + lane16];
        uint4 v7 = h4[(size_t)s7 * 16 + lane16];
        addrow(ax, v0); addrow(ay, v1); addrow(ax, v2); addrow(ay, v3);
        addrow(ax, v4); addrow(ay, v5); addrow(ax, v6); addrow(ay, v7);
    }
    float sc = 1.0f / fmaxf((float)deg, 1.0f);
    u32x4v o;
    o.x = pack2((ax[0] + ay[0]) * sc, (ax[1] + ay[1]) * sc);
    o.y = pack2((ax[2] + ay[2]) * sc, (ax[3] + ay[3]) * sc);
    o.z = pack2((ax[4] + ay[4]) * sc, (ax[5] + ay[5]) * sc);
    o.w = pack2((ax[6] + ay[6]) * sc, (ax[7] + ay[7]) * sc);
    __builtin_nontemporal_store(o, (u32x4v*)agg + ((size_t)n * 16 + lane16));
}

// ---- MFMA linear, BK=128: 2 stages (agg@Wl, then h@Wr), 4 barriers total.
// BM=64, BN=128; 782 blocks, 4 waves 2x2 (wave 32x64 via 2x4 MFMAs x4 ksteps).
// LDS: A 16 KB + B 32 KB = 48 KB, [kchunk][row]x16B GLL-compatible layout.
__global__ __launch_bounds__(256) void k_linear(const ushort_t* __restrict__ agg,
                                                const ushort_t* h,  // may alias out
                                                const ushort_t* __restrict__ Wl,
                                                const ushort_t* __restrict__ Wr,
                                                const float* __restrict__ bias,
                                                ushort_t* out) {
    __shared__ uint4 Alds4[1024];   // 16 KB: 64 rows x 128 k bf16
    __shared__ uint4 Blds4[2048];   // 32 KB: 128 rows x 128 k bf16
    ushort_t* Alds = (ushort_t*)Alds4;
    ushort_t* Blds = (ushort_t*)Blds4;

    int t = threadIdx.x;
    int w = t >> 6;
    int lane = t & 63;
    int bm = blockIdx.x * 64;
    int wm = (w & 1) * 32;
    int wn = (w >> 1) * 64;
    int lrow = lane & 15;
    int kg = lane >> 4;

    f32x4 acc[2][4];
#pragma unroll
    for (int i = 0; i < 2; i++)
#pragma unroll
        for (int j = 0; j < 4; j++) acc[i][j] = (f32x4){0.f, 0.f, 0.f, 0.f};

#pragma unroll
    for (int iter = 0; iter < 2; iter++) {
        const ushort_t* A = iter ? h : agg;
        const ushort_t* W = iter ? Wr : Wl;

        __syncthreads();  // LDS safe to overwrite
        // A: 1024 slots of 16B, 4/thread. chunk = p*4+w, row = lane.
#pragma unroll
        for (int p = 0; p < 4; p++) {
            int chunkA = p * 4 + w;
            const ushort_t* gA = A + (size_t)(bm + lane) * F + chunkA * 8;
            ushort_t* lA = Alds + (size_t)(chunkA * 64) * 8;
            __builtin_amdgcn_global_load_lds(
                (const __attribute__((address_space(1))) void*)gA,
                (__attribute__((address_space(3))) void*)lA, 16, 0, 0);
        }
        // B: 2048 slots of 16B, 8/thread. chunk = p*2+(w>>1), row = (w&1)*64+lane.
#pragma unroll
        for (int p = 0; p < 8; p++) {
            int chunkB = p * 2 + (w >> 1);
            int rbase = (w & 1) * 64;
            const ushort_t* gB = W + (size_t)(rbase + lane) * F + chunkB * 8;
            ushort_t* lB = Blds + (size_t)(chunkB * 128 + rbase) * 8;
            __builtin_amdgcn_global_load_lds(
                (const __attribute__((address_space(1))) void*)gB,
                (__attribute__((address_space(3))) void*)lB, 16, 0, 0);
        }
        __syncthreads();

#pragma unroll
        for (int ks = 0; ks < 4; ks++) {
            bf16x8 af[2], bfr[4];
#pragma unroll
            for (int i = 0; i < 2; i++)
                af[i] = *(const bf16x8*)(Alds +
                    (size_t)((ks * 4 + kg) * 64 + wm + i * 16 + lrow) * 8);
#pragma unroll
            for (int j = 0; j < 4; j++)
                bfr[j] = *(const bf16x8*)(Blds +
                    (size_t)((ks * 4 + kg) * 128 + wn + j * 16 + lrow) * 8);
#pragma unroll
            for (int i = 0; i < 2; i++)
#pragma unroll
                for (int j = 0; j < 4; j++)
                    acc[i][j] = __builtin_amdgcn_mfma_f32_16x16x32_bf16(
                        af[i], bfr[j], acc[i][j], 0, 0, 0);
        }
    }

    // epilogue: C/D map col=lane&15, row=(lane>>4)*4+reg.
    // Pad rows (>=N_NODES) written as EXPLICIT ZEROS (next layer's ZROW).
    int quad = lane >> 4;
#pragma unroll
    for (int j = 0; j < 4; j++) {
        int c = wn + j * 16 + lrow;
        float bj = bias[c];
#pragma unroll
        for (int i = 0; i < 2; i++) {
#pragma unroll
            for (int r = 0; r < 4; r++) {
                int row = bm + wm + i * 16 + quad * 4 + r;
                float v = (row < N_NODES) ? fmaxf(acc[i][j][r] + bj, 0.0f) : 0.0f;
                out[(size_t)row * F + c] = f2bf(v);
            }
        }
    }
}

// ---- mean pool: block per graph, 256 thr = 64 col-pairs x 4 row-phases.
// uint loads (2 cols, full 256B/wave coalescing), LDS 4-way reduce.
__global__ __launch_bounds__(256) void k_pool(const ushort_t* __restrict__ h,
                                              const int* __restrict__ batch,
                                              float* __restrict__ out) {
    __shared__ float red[4][128];
    int g = blockIdx.x;
    int t = threadIdx.x;
    int cp = t & 63;          // col pair 0..63 -> cols 2cp, 2cp+1
    int rp = t >> 6;          // row phase 0..3
    int lo = 0, hi = N_NODES;
    while (lo < hi) {
        int m = (lo + hi) >> 1;
        if (batch[m] < g) lo = m + 1; else hi = m;
    }
    int start = lo;
    lo = start; hi = N_NODES;
    while (lo < hi) {
        int m = (lo + hi) >> 1;
        if (batch[m] < g + 1) lo = m + 1; else hi = m;
    }
    int end = lo;
    float s0 = 0.0f, s1 = 0.0f;
    for (int n = start + rp; n < end; n += 4) {
        uint_t v = *(const uint_t*)&h[(size_t)n * F + cp * 2];
        s0 += __uint_as_float(v << 16);
        s1 += __uint_as_float(v & 0xFFFF0000u);
    }
    red[rp][cp * 2] = s0;
    red[rp][cp * 2 + 1] = s1;
    __syncthreads();
    if (t < 128) {
        float r = red[0][t] + red[1][t] + red[2][t] + red[3][t];
        out[g * F + t] = r / fmaxf((float)(end - start), 1.0f);
    }
}

extern "C" void kernel_launch(void* const* d_in, const int* in_sizes, int n_in,
                              void* d_out, int out_size, void* d_ws, size_t ws_size,
                              hipStream_t stream) {
    const float* x   = (const float*)d_in[0];
    const int*   ei  = (const int*)d_in[1];
    const int* batch = (const int*)d_in[2];
    const float* W1l = (const float*)d_in[3];
    const float* W1r = (const float*)d_in[4];
    const float* b1  = (const float*)d_in[5];
    const float* W2l = (const float*)d_in[6];
    const float* W2r = (const float*)d_in[7];
    const float* b2  = (const float*)d_in[8];
    const float* W3l = (const float*)d_in[9];
    const float* W3r = (const float*)d_in[10];
    const float* b3  = (const float*)d_in[11];
    float* out = (float*)d_out;

    const int* src = ei;
    const int* dst = ei + N_EDGES;

    // ws layout: X/HA/HB/AGG (4 x 12.81 MB) + WB (0.19) + ell (6.4) + cnt
    ushort_t* X   = (ushort_t*)d_ws;          // NP*128 bf16
    ushort_t* HA  = X + (size_t)NP * F;
    ushort_t* HB  = HA + (size_t)NP * F;
    ushort_t* AGG = HB + (size_t)NP * F;
    ushort_t* WB  = AGG + (size_t)NP * F;     // 6*16384 bf16
    ushort_t* ell = WB + 6 * 16384;           // 50000*64 ushort
    int* cnt = (int*)(ell + (size_t)50000 * 64);

    // pad cnt to 1 counter / 64B line (stride 16 ints) if ws has room (+3 MB)
    size_t cnt_off = (char*)cnt - (char*)d_ws;
    int cs = (ws_size >= cnt_off + (size_t)50176 * 64) ? 16 : 1;

    const ushort_t* Wb1l = WB;
    const ushort_t* Wb1r = WB + 16384;
    const ushort_t* Wb2l = WB + 2 * 16384;
    const ushort_t* Wb2r = WB + 3 * 16384;
    const ushort_t* Wb3l = WB + 4 * 16384;
    const ushort_t* Wb3r = WB + 5 * 16384;

    (void)hipMemsetAsync(cnt, 0, (size_t)50176 * 4 * cs, stream);
    k_build<<<FILL_BLOCKS + CASTX_BLOCKS + CASTW_BLOCKS, 256, 0, stream>>>(
        x, W1l, W1r, W2l, W2r, W3l, W3r, src, dst, X, WB, cnt, ell, cs);

    const int gatherBlocks = (N_NODES * 16 + 255) / 256;  // 3125
    const int linearBlocks = NP / 64;                     // 782

    k_gather<<<gatherBlocks, 256, 0, stream>>>(X, ell, cnt, AGG, cs);
    k_linear<<<linearBlocks, 256, 0, stream>>>(AGG, X, Wb1l, Wb1r, b1, HA);
    k_gather<<<gatherBlocks, 256, 0, stream>>>(HA, ell, cnt, AGG, cs);
    k_linear<<<linearBlocks, 256, 0, stream>>>(AGG, HA, Wb2l, Wb2r, b2, HB);
    k_gather<<<gatherBlocks, 256, 0, stream>>>(HB, ell, cnt, AGG, cs);
    k_linear<<<linearBlocks, 256, 0, stream>>>(AGG, HB, Wb3l, Wb3r, b3, HA);

    k_pool<<<N_GRAPHS, 256, 0, stream>>>(HA, batch, out);
}